// Round 2
// baseline (24590.268 us; speedup 1.0000x reference)
//
#include <hip/hip_runtime.h>

typedef _Float16 f16;
typedef f16 f16x2 __attribute__((ext_vector_type(2)));
typedef f16 f16x8 __attribute__((ext_vector_type(8)));
typedef float f32x4 __attribute__((ext_vector_type(4)));

#define TT 1024
#define BB 32
#define DD 1024
#define RR 256

// Packed f16 weights.
// g_VP2 unit (j,t), j in [0,16): 32B = { V[2*q3][8c..8c+8), V[2*q3+1][8c..8c+8) }
//   where q3 = t>>3, s3 = t&7, c = 16*s3 + ((j+s3)&15).  Byte off = (j*1024+t)*32.
// g_UP4 unit (j,t), j in [0,8): 64B = { U[4*q+k][8c2..8c2+8), k=0..3 }
//   where q = t>>2, z4 = t&3, c2 = 8*z4 + ((j+z4)&7).  Byte off = (j*1024+t)*64.
__device__ __align__(16) f16 g_VP2[16 * 1024 * 16];   // 512 KB
__device__ __align__(16) f16 g_UP4[8 * 1024 * 32];    // 512 KB

__device__ __forceinline__ float dot2f(f16x2 a, f16x2 b, float c) {
#if __has_builtin(__builtin_amdgcn_fdot2)
    return __builtin_amdgcn_fdot2(a, b, c, false);
#else
    return c + (float)a[0] * (float)b[0] + (float)a[1] * (float)b[1];
#endif
}

__device__ __forceinline__ float sigm_f(float x) { return 1.0f / (1.0f + __expf(-x)); }
__device__ __forceinline__ float tanh_f(float x) { return 1.0f - 2.0f / (1.0f + __expf(2.0f * x)); }

// raw barrier: LDS ordering only, global loads stay in flight across it
__device__ __forceinline__ void wg_barrier() {
    asm volatile("s_waitcnt lgkmcnt(0)" ::: "memory");
    __builtin_amdgcn_s_barrier();
    asm volatile("" ::: "memory");
}

// ---------------------------------------------------------------------------
// Kernel 1: fused pre-GEMM (unchanged).  ax = x@Wa^T + ba ; wx = x@Wx^T + b
// ---------------------------------------------------------------------------
__global__ __launch_bounds__(256)
void fused_pregemm(const float* __restrict__ X, const float* __restrict__ Wa,
                   const float* __restrict__ Wx, const float* __restrict__ ba,
                   const float* __restrict__ bb, f16* __restrict__ axo,
                   f16* __restrict__ wxo)
{
    __shared__ __align__(16) f16 lA[64][40];
    __shared__ __align__(16) f16 lB[64][40];
    __shared__ __align__(16) f16 lC[64][40];

    const int tid = threadIdx.x;
    const int w   = tid >> 6;
    const int l   = tid & 63;
    const int la  = l & 15;
    const int qd  = l >> 4;
    const int m0  = blockIdx.x * 64;
    const int n0  = blockIdx.y * 64;
    const int sr  = tid >> 2;
    const int sk  = (tid & 3) * 8;

    f32x4 accA[4] = {};
    f32x4 accX[4] = {};

    for (int k0 = 0; k0 < DD; k0 += 32) {
        {
            const float* pX = X + (size_t)(m0 + sr) * DD + k0 + sk;
            float4 v0 = *(const float4*)pX;
            float4 v1 = *(const float4*)(pX + 4);
            f16x8 x8 = {(f16)v0.x, (f16)v0.y, (f16)v0.z, (f16)v0.w,
                        (f16)v1.x, (f16)v1.y, (f16)v1.z, (f16)v1.w};
            *(f16x8*)&lA[sr][sk] = x8;

            const float* pA = Wa + (size_t)(n0 + sr) * DD + k0 + sk;
            v0 = *(const float4*)pA;
            v1 = *(const float4*)(pA + 4);
            f16x8 a8 = {(f16)v0.x, (f16)v0.y, (f16)v0.z, (f16)v0.w,
                        (f16)v1.x, (f16)v1.y, (f16)v1.z, (f16)v1.w};
            *(f16x8*)&lB[sr][sk] = a8;

            const float* pW = Wx + (size_t)(n0 + sr) * DD + k0 + sk;
            v0 = *(const float4*)pW;
            v1 = *(const float4*)(pW + 4);
            f16x8 w8 = {(f16)v0.x, (f16)v0.y, (f16)v0.z, (f16)v0.w,
                        (f16)v1.x, (f16)v1.y, (f16)v1.z, (f16)v1.w};
            *(f16x8*)&lC[sr][sk] = w8;
        }
        __syncthreads();

        f16x8 af = *(const f16x8*)&lA[16 * w + la][qd * 8];
        #pragma unroll
        for (int c = 0; c < 4; c++) {
            f16x8 b1 = *(const f16x8*)&lB[16 * c + la][qd * 8];
            f16x8 b2 = *(const f16x8*)&lC[16 * c + la][qd * 8];
            accA[c] = __builtin_amdgcn_mfma_f32_16x16x32_f16(af, b1, accA[c], 0, 0, 0);
            accX[c] = __builtin_amdgcn_mfma_f32_16x16x32_f16(af, b2, accX[c], 0, 0, 0);
        }
        __syncthreads();
    }

    #pragma unroll
    for (int c = 0; c < 4; c++) {
        const int n = n0 + 16 * c + la;
        const float bav = ba[n];
        const float bbv = bb[n];
        #pragma unroll
        for (int r = 0; r < 4; r++) {
            const int m = m0 + 16 * w + qd * 4 + r;
            axo[(size_t)m * DD + n] = (f16)(accA[c][r] + bav);
            wxo[(size_t)m * DD + n] = (f16)(accX[c][r] + bbv);
        }
    }
}

// ---------------------------------------------------------------------------
// Kernel 1b: one-time f32 -> f16 weight pack.  grid = 16 blocks (= j).
// ---------------------------------------------------------------------------
__global__ __launch_bounds__(1024)
void pack_weights(const float* __restrict__ V, const float* __restrict__ U)
{
    const int j = blockIdx.x;
    const int t = threadIdx.x;
    {
        const int q3 = t >> 3, s3 = t & 7;
        const int c  = 16 * s3 + ((j + s3) & 15);
        const float* s0 = V + (size_t)(2 * q3)     * DD + 8 * c;
        const float* s1 = V + (size_t)(2 * q3 + 1) * DD + 8 * c;
        f16x8 a, bvec;
        #pragma unroll
        for (int k = 0; k < 8; k++) { a[k] = (f16)s0[k]; bvec[k] = (f16)s1[k]; }
        f16x8* dst = (f16x8*)g_VP2 + ((size_t)j * 1024 + t) * 2;
        dst[0] = a; dst[1] = bvec;
    }
    if (j < 8) {
        const int q = t >> 2, z4 = t & 3;
        const int c2 = 8 * z4 + ((j + z4) & 7);
        f16x8* dst = (f16x8*)g_UP4 + ((size_t)j * 1024 + t) * 4;
        #pragma unroll
        for (int k = 0; k < 4; k++) {
            const float* su = U + (size_t)(4 * q + k) * RR + 8 * c2;
            f16x8 u8;
            #pragma unroll
            for (int m = 0; m < 8; m++) u8[m] = (f16)su[m];
            dst[k] = u8;
        }
    }
}

// ---------------------------------------------------------------------------
// Kernel 2: scan with register-pipelined weight streaming.
//   stage1: thread (q3=tid>>3, s3=tid&7) owns rows {2q3, 2q3+1} x d-slice
//           [128*s3,+128): 16 ds_read, 32 global b128, shfl_xor{1,2,4} reduce.
//   stage2: thread (q=tid>>2, z4=tid&3) owns rows {4q..4q+3} x p-slice
//           [64*z4,+64): 8 ds_read, 32 global b128, shfl_xor{1,2} butterfly,
//           thread keeps e = tid.
//   Double-buffered 8-load slots, prefetch distance 2, kept in flight across
//   raw barriers (no vmcnt drain).
// ---------------------------------------------------------------------------
template<int S>
__device__ __forceinline__ void issue_s1(f16x8* buf, const f16x8* vW, int tid) {
    #pragma unroll
    for (int k = 0; k < 4; k++) {
        unsigned idx = ((unsigned)(4 * S + k) << 10) + (unsigned)tid;
        buf[2 * k]     = vW[idx * 2u];
        buf[2 * k + 1] = vW[idx * 2u + 1u];
    }
}

template<int S>
__device__ __forceinline__ void comp_s1(const f16x8* buf, const f16x8* hch, int s3,
                                        float& aA0, float& aA1, float& aB0, float& aB1) {
    #pragma unroll
    for (int k = 0; k < 4; k++) {
        const int j = 4 * S + k;
        f16x8 hv = hch[16 * s3 + ((j + s3) & 15)];
        f16x8 wA = buf[2 * k], wB = buf[2 * k + 1];
        f16x2 h0 = {hv[0], hv[1]}, h1 = {hv[2], hv[3]};
        f16x2 h2v = {hv[4], hv[5]}, h3 = {hv[6], hv[7]};
        f16x2 t0 = {wA[0], wA[1]}, t1 = {wA[2], wA[3]};
        f16x2 t2 = {wA[4], wA[5]}, t3 = {wA[6], wA[7]};
        aA0 = dot2f(t0, h0, aA0);  aA1 = dot2f(t1, h1, aA1);
        aA0 = dot2f(t2, h2v, aA0); aA1 = dot2f(t3, h3, aA1);
        f16x2 r0 = {wB[0], wB[1]}, r1 = {wB[2], wB[3]};
        f16x2 r2 = {wB[4], wB[5]}, r3 = {wB[6], wB[7]};
        aB0 = dot2f(r0, h0, aB0);  aB1 = dot2f(r1, h1, aB1);
        aB0 = dot2f(r2, h2v, aB0); aB1 = dot2f(r3, h3, aB1);
    }
}

template<int S>
__device__ __forceinline__ void issue_s2(f16x8* buf, const f16x8* uW, int tid) {
    #pragma unroll
    for (int k = 0; k < 2; k++) {
        unsigned idx = ((unsigned)(2 * S + k) << 10) + (unsigned)tid;
        #pragma unroll
        for (int m = 0; m < 4; m++)
            buf[4 * k + m] = uW[idx * 4u + (unsigned)m];
    }
}

template<int S>
__device__ __forceinline__ void comp_s2(const f16x8* buf, const f16x8* pch, int z4,
                                        float& u0, float& u1, float& u2, float& u3) {
    #pragma unroll
    for (int k = 0; k < 2; k++) {
        const int j = 2 * S + k;
        f16x8 pv = pch[8 * z4 + ((j + z4) & 7)];
        f16x2 p0 = {pv[0], pv[1]}, p1 = {pv[2], pv[3]};
        f16x2 p2 = {pv[4], pv[5]}, p3 = {pv[6], pv[7]};
        {
            f16x8 w = buf[4 * k + 0];
            f16x2 w0 = {w[0], w[1]}, w1 = {w[2], w[3]}, w2 = {w[4], w[5]}, w3 = {w[6], w[7]};
            u0 = dot2f(w0, p0, u0); u0 = dot2f(w1, p1, u0);
            u0 = dot2f(w2, p2, u0); u0 = dot2f(w3, p3, u0);
        }
        {
            f16x8 w = buf[4 * k + 1];
            f16x2 w0 = {w[0], w[1]}, w1 = {w[2], w[3]}, w2 = {w[4], w[5]}, w3 = {w[6], w[7]};
            u1 = dot2f(w0, p0, u1); u1 = dot2f(w1, p1, u1);
            u1 = dot2f(w2, p2, u1); u1 = dot2f(w3, p3, u1);
        }
        {
            f16x8 w = buf[4 * k + 2];
            f16x2 w0 = {w[0], w[1]}, w1 = {w[2], w[3]}, w2 = {w[4], w[5]}, w3 = {w[6], w[7]};
            u2 = dot2f(w0, p0, u2); u2 = dot2f(w1, p1, u2);
            u2 = dot2f(w2, p2, u2); u2 = dot2f(w3, p3, u2);
        }
        {
            f16x8 w = buf[4 * k + 3];
            f16x2 w0 = {w[0], w[1]}, w1 = {w[2], w[3]}, w2 = {w[4], w[5]}, w3 = {w[6], w[7]};
            u3 = dot2f(w0, p0, u3); u3 = dot2f(w1, p1, u3);
            u3 = dot2f(w2, p2, u3); u3 = dot2f(w3, p3, u3);
        }
    }
}

__global__ __launch_bounds__(1024, 4)
void rnn_scan(const f16* __restrict__ ax, const f16* __restrict__ wx,
              const float* __restrict__ h0, float* __restrict__ out,
              float* __restrict__ hout)
{
    const int b   = blockIdx.x;
    const int tid = threadIdx.x;
    const int s3  = tid & 7;
    const int q3  = tid >> 3;
    const int z4  = tid & 3;

    __shared__ __align__(16) f16 h2[DD];
    __shared__ __align__(4)  f16 pl[RR];

    const f16x8* vW  = (const f16x8*)g_VP2;
    const f16x8* uW  = (const f16x8*)g_UP4;
    const f16x8* hch = (const f16x8*)h2;
    const f16x8* pch = (const f16x8*)pl;

    const float h0v = h0[(size_t)b * DD + tid];
    float hreg = h0v;
    h2[tid] = (f16)h0v;
    hout[(size_t)b * DD + tid] = h0v;

    const f16* axp   = ax  + (size_t)b * DD + tid;
    const f16* wxp   = wx  + (size_t)b * DD + tid;
    float*     outp  = out + (size_t)b * DD + tid;
    float*     houtp = hout + (size_t)BB * DD + (size_t)b * DD + tid;

    f16x8 bufA[8], bufB[8];

    // prologue: first two stage-1 slots in flight
    issue_s1<0>(bufA, vW, tid);
    issue_s1<1>(bufB, vW, tid);
    wg_barrier();                       // h2 visible to all waves

    #pragma unroll 1
    for (int t = 0; t < TT; t++) {
        const float axv = (float)*axp;
        const float wxv = (float)*wxp;

        // ---- stage 1 (pipelined): consume slot, refill 2 ahead
        float aA0 = 0.f, aA1 = 0.f, aB0 = 0.f, aB1 = 0.f;
        comp_s1<0>(bufA, hch, s3, aA0, aA1, aB0, aB1);  issue_s1<2>(bufA, vW, tid);
        comp_s1<1>(bufB, hch, s3, aA0, aA1, aB0, aB1);  issue_s1<3>(bufB, vW, tid);
        comp_s1<2>(bufA, hch, s3, aA0, aA1, aB0, aB1);  issue_s2<0>(bufA, uW, tid);
        comp_s1<3>(bufB, hch, s3, aA0, aA1, aB0, aB1);  issue_s2<1>(bufB, uW, tid);

        float pA = aA0 + aA1, pB = aB0 + aB1;
        pA += __shfl_xor(pA, 1); pA += __shfl_xor(pA, 2); pA += __shfl_xor(pA, 4);
        pB += __shfl_xor(pB, 1); pB += __shfl_xor(pB, 2); pB += __shfl_xor(pB, 4);
        if (s3 == 0) {
            f16x2 pp; pp[0] = (f16)pA; pp[1] = (f16)pB;
            *(f16x2*)&pl[2 * q3] = pp;
        }
        wg_barrier();

        // ---- stage 2 (pipelined); last two slots prefetch next step's stage 1
        float u0 = 0.f, u1 = 0.f, u2 = 0.f, u3 = 0.f;
        comp_s2<0>(bufA, pch, z4, u0, u1, u2, u3);  issue_s2<2>(bufA, uW, tid);
        comp_s2<1>(bufB, pch, z4, u0, u1, u2, u3);  issue_s2<3>(bufB, uW, tid);
        comp_s2<2>(bufA, pch, z4, u0, u1, u2, u3);  issue_s1<0>(bufA, vW, tid);
        comp_s2<3>(bufB, pch, z4, u0, u1, u2, u3);  issue_s1<1>(bufB, vW, tid);

        u0 += __shfl_xor(u0, 1); u1 += __shfl_xor(u1, 1);
        u2 += __shfl_xor(u2, 1); u3 += __shfl_xor(u3, 1);
        u0 += __shfl_xor(u0, 2); u1 += __shfl_xor(u1, 2);
        u2 += __shfl_xor(u2, 2); u3 += __shfl_xor(u3, 2);
        float uu = (z4 == 0) ? u0 : (z4 == 1) ? u1 : (z4 == 2) ? u2 : u3;

        // ---- elementwise, e = tid
        uu += wxv;
        const float vv = tanh_f(uu);
        const float aa = sigm_f(axv);
        const float hn = aa * hreg + (1.0f - aa) * vv;
        const float so = hn * hn * sigm_f(hn);   // h * silu(h)
        *outp  = so;
        *houtp = hn;
        hreg = hn;
        h2[tid] = (f16)hn;
        axp += BB * DD; wxp += BB * DD; outp += BB * DD; houtp += BB * DD;
        wg_barrier();
    }
}

extern "C" void kernel_launch(void* const* d_in, const int* in_sizes, int n_in,
                              void* d_out, int out_size, void* d_ws, size_t ws_size,
                              hipStream_t stream) {
    (void)in_sizes; (void)n_in; (void)out_size; (void)ws_size;
    const float* x  = (const float*)d_in[0];
    const float* h0 = (const float*)d_in[1];
    const float* Wa = (const float*)d_in[2];
    const float* ba = (const float*)d_in[3];
    const float* U  = (const float*)d_in[4];
    const float* V  = (const float*)d_in[5];
    const float* Wx = (const float*)d_in[6];
    const float* bb = (const float*)d_in[7];

    float* out  = (float*)d_out;                    // output [T,B,D]
    float* hout = out + (size_t)TT * BB * DD;       // h [T+1,B,D]

    f16* ax16 = (f16*)d_ws;                         // 64 MiB
    f16* wx16 = ax16 + (size_t)TT * BB * DD;        // 64 MiB

    pack_weights<<<dim3(16), dim3(1024), 0, stream>>>(V, U);
    dim3 g1(512, 16);
    fused_pregemm<<<g1, dim3(256), 0, stream>>>(x, Wa, Wx, ba, bb, ax16, wx16);
    rnn_scan<<<dim3(BB), dim3(1024), 0, stream>>>(ax16, wx16, h0, out, hout);
}